// Round 9
// baseline (195.610 us; speedup 1.0000x reference)
//
#include <hip/hip_runtime.h>
#include <math.h>

#define BB   4
#define TT   4096
#define DIN  1024
#define DST  2048
#define MM   (BB*TT)     // 16384
#define CHK  32          // scan chunks per sequence
#define CLEN (TT/CHK)    // 128

typedef __bf16 bf16x8 __attribute__((ext_vector_type(8)));
typedef float  f32x4  __attribute__((ext_vector_type(4)));

__device__ __forceinline__ unsigned short f2bf(float f) {
    union { float f; unsigned u; } v; v.f = f;
    unsigned r = v.u + 0x7FFFu + ((v.u >> 16) & 1u);   // RNE
    return (unsigned short)(r >> 16);
}
__device__ __forceinline__ float bf2f(unsigned short h) {
    union { unsigned u; float f; } v; v.u = ((unsigned)h) << 16;
    return v.f;
}
__device__ __forceinline__ float sigm(float x) { return 1.f / (1.f + __expf(-x)); }

// ---------------------------------------------------------------------------
// fused fp32 -> bf16 conversion of u, W_in, W_out in ONE launch.
// ---------------------------------------------------------------------------
#define N_U4 (MM * DIN / 4)          // 4,194,304
#define N_W4 (DST * DIN / 4)         //   524,288

__global__ __launch_bounds__(256)
void cvt_all_kernel(const float* __restrict__ u,
                    const float* __restrict__ W_in,
                    const float* __restrict__ W_out,
                    unsigned short* __restrict__ uA,
                    unsigned short* __restrict__ wA,
                    unsigned short* __restrict__ wB)
{
    int i = blockIdx.x * 256 + threadIdx.x;
    const float* src; unsigned short* dst; int idx;
    if (i < N_U4)                { src = u;     dst = uA; idx = i; }
    else if (i < N_U4 + N_W4)    { src = W_in;  dst = wA; idx = i - N_U4; }
    else                         { src = W_out; dst = wB; idx = i - N_U4 - N_W4; }
    float4 f = reinterpret_cast<const float4*>(src)[idx];
    ushort4 o;
    o.x = f2bf(f.x); o.y = f2bf(f.y); o.z = f2bf(f.z); o.w = f2bf(f.w);
    reinterpret_cast<ushort4*>(dst)[idx] = o;
}

// ---------------------------------------------------------------------------
// m97-structure bf16 NT MFMA GEMM (proven 912 TF @4k): 128x128 tile, BK=64,
// 256 threads = 4 waves (2x2), wave tile 64x64, SINGLE 32 KiB LDS buffer,
// 2-barrier loop, no setprio, no explicit vmcnt (compiler drains at barrier).
// Occupancy target: 3 blocks/CU (12 waves/CU) via __launch_bounds__(256,3) —
// independent blocks at different phases give MFMA||LDS||VMEM overlap (m114).
// XOR swizzle col8 ^= (row&7) on stage-source AND ds_read (0-conflict).
// C[m,n] = sum_k A[m,k]*B[n,k];  A: MxK, B: NxK, both bf16 row-major.
// FUSE=false: Obf = bf16(acc)                   (GEMM1)
// FUSE=true : Of  = acc + bf2f(Ubf)*Dv[col]     (GEMM2)
// ---------------------------------------------------------------------------
template<int K, int NB, bool FUSE>
__global__ __launch_bounds__(256, 3)
void gemm_m97(const unsigned short* __restrict__ A,
              const unsigned short* __restrict__ B,
              unsigned short* __restrict__ Obf,
              float* __restrict__ Of,
              const unsigned short* __restrict__ Ubf,
              const float* __restrict__ Dv)
{
    constexpr int N  = NB * 128;
    constexpr int NT = K / 64;
    __shared__ __align__(16) unsigned short lds[16384];   // A 16KB + B 16KB

    // XCD-aware bijective swizzle (nwg % 8 == 0: 2048 / 1024 blocks)
    const int nwg = gridDim.x;
    const int bid = blockIdx.x;
    const int swz = (bid & 7) * (nwg >> 3) + (bid >> 3);
    const int bm = swz / NB, bn = swz % NB;

    const int tid  = threadIdx.x;
    const int lane = tid & 63;
    const int wid  = tid >> 6;          // 0..3
    const int wr   = wid >> 1;          // 0..1  (64-row band)
    const int wc   = wid & 1;           // 0..1  (64-col band)
    const int fr   = lane & 15, fq = lane >> 4;

    // --- staging: linear LDS dest, pre-swizzled global source col ---
    const int srow = tid >> 3;                                  // 0..31
    const int scol = (((tid & 7) ^ (srow & 7)) << 3);           // swizzled col
    const unsigned short* Ag = A + (size_t)(bm * 128 + srow) * K + scol;
    const unsigned short* Bg = B + (size_t)(bn * 128 + srow) * K + scol;

    auto stage = [&](int t) {   // 8 loads/thread: A rows r*32+srow, B same
        const size_t kof = (size_t)t * 64;
#pragma unroll
        for (int r = 0; r < 4; ++r)
            __builtin_amdgcn_global_load_lds(
                (const __attribute__((address_space(1))) void*)(Ag + kof + (size_t)(r * 32) * K),
                (__attribute__((address_space(3))) void*)(&lds[r * 2048 + tid * 8]),
                16, 0, 0);
#pragma unroll
        for (int r = 0; r < 4; ++r)
            __builtin_amdgcn_global_load_lds(
                (const __attribute__((address_space(1))) void*)(Bg + kof + (size_t)(r * 32) * K),
                (__attribute__((address_space(3))) void*)(&lds[8192 + r * 2048 + tid * 8]),
                16, 0, 0);
    };

    // --- frag read addressing (read-side swizzle: row&7 == fr&7) ---
    const int c0 = ((fq ^ (fr & 7)) << 3);          // kk=0 col group
    const int c1 = (((4 + fq) ^ (fr & 7)) << 3);    // kk=1 col group
    const int aBase = (wr * 64 + fr) * 64;                  // + m*1024
    const int bBase = 8192 + (wc * 64 + fr) * 64;           // + n*1024

    f32x4 acc[4][4];
#pragma unroll
    for (int m = 0; m < 4; ++m)
#pragma unroll
        for (int n = 0; n < 4; ++n) {
            acc[m][n][0] = 0.f; acc[m][n][1] = 0.f;
            acc[m][n][2] = 0.f; acc[m][n][3] = 0.f;
        }

    for (int t = 0; t < NT; ++t) {
        __syncthreads();            // all reads of buffer done (prev iter)
        stage(t);
        __syncthreads();            // compiler drains vmcnt before barrier

        bf16x8 af[4], bfv[4];
        // kk = 0
#pragma unroll
        for (int m = 0; m < 4; ++m)
            af[m] = *reinterpret_cast<const bf16x8*>(&lds[aBase + m * 1024 + c0]);
#pragma unroll
        for (int n = 0; n < 4; ++n)
            bfv[n] = *reinterpret_cast<const bf16x8*>(&lds[bBase + n * 1024 + c0]);
#pragma unroll
        for (int m = 0; m < 4; ++m)
#pragma unroll
            for (int n = 0; n < 4; ++n)
                acc[m][n] = __builtin_amdgcn_mfma_f32_16x16x32_bf16(
                    af[m], bfv[n], acc[m][n], 0, 0, 0);
        // kk = 1
#pragma unroll
        for (int m = 0; m < 4; ++m)
            af[m] = *reinterpret_cast<const bf16x8*>(&lds[aBase + m * 1024 + c1]);
#pragma unroll
        for (int n = 0; n < 4; ++n)
            bfv[n] = *reinterpret_cast<const bf16x8*>(&lds[bBase + n * 1024 + c1]);
#pragma unroll
        for (int m = 0; m < 4; ++m)
#pragma unroll
            for (int n = 0; n < 4; ++n)
                acc[m][n] = __builtin_amdgcn_mfma_f32_16x16x32_bf16(
                    af[m], bfv[n], acc[m][n], 0, 0, 0);
    }

    // --- epilogue.  C/D layout: col = lane&15, row = fq*4 + reg ---
    const int row0 = bm * 128 + wr * 64 + fq * 4;
    const int col0 = bn * 128 + wc * 64 + fr;
    if (FUSE) {
#pragma unroll
        for (int n = 0; n < 4; ++n) {
            const int col = col0 + n * 16;
            const float d = Dv[col];
#pragma unroll
            for (int m = 0; m < 4; ++m)
#pragma unroll
                for (int r = 0; r < 4; ++r) {
                    const size_t idx = (size_t)(row0 + m * 16 + r) * N + col;
                    Of[idx] = acc[m][n][r] + bf2f(Ubf[idx]) * d;
                }
        }
    } else {
#pragma unroll
        for (int m = 0; m < 4; ++m)
#pragma unroll
            for (int r = 0; r < 4; ++r) {
                const size_t ro = (size_t)(row0 + m * 16 + r) * N;
#pragma unroll
                for (int n = 0; n < 4; ++n)
                    Obf[ro + col0 + n * 16] = f2bf(acc[m][n][r]);
            }
    }
}

// ---------------------------------------------------------------------------
// Chunked scan, 3 phases. up is bf16 [B][T][DST] = raw u_proj (unscaled).
// ---------------------------------------------------------------------------
__global__ __launch_bounds__(256)
void scan1_kernel(const unsigned short* __restrict__ up,
                  const float* __restrict__ logl,
                  float* __restrict__ fin)
{
    const int gid = blockIdx.x * 256 + threadIdx.x;   // B*CHK*(DST/2)
    const int sp  = gid & (DST / 2 - 1);
    const int bc  = gid >> 10;                         // b*CHK + c
    const int c   = bc & (CHK - 1), b = bc >> 5;
    const int s0  = sp * 2;
    const float lam0 = sigm(logl[s0]),  lam1 = sigm(logl[s0 + 1]);
    const float o0 = 1.f - lam0, o1 = 1.f - lam1;
    const ushort2* p = reinterpret_cast<const ushort2*>(
        up + ((size_t)b * TT + (size_t)c * CLEN) * DST + s0);
    float x0 = 0.f, x1 = 0.f;
    for (int t = 0; t < CLEN; ++t) {
        ushort2 v = p[(size_t)t * (DST / 2)];
        x0 = fmaf(lam0, x0, o0 * bf2f(v.x));
        x1 = fmaf(lam1, x1, o1 * bf2f(v.y));
    }
    reinterpret_cast<float2*>(fin + (size_t)bc * DST + s0)[0] = make_float2(x0, x1);
}

__global__ __launch_bounds__(256)
void scan2_kernel(float* __restrict__ fin, const float* __restrict__ logl)
{
    const int gid = blockIdx.x * 256 + threadIdx.x;   // B*DST
    const int s = gid & (DST - 1), b = gid >> 11;
    const float lam = sigm(logl[s]);
    float lamL = lam;
#pragma unroll
    for (int i = 0; i < 7; ++i) lamL *= lamL;          // lam^128
    float x = 0.f;
    float* f = fin + (size_t)b * CHK * DST + s;
#pragma unroll
    for (int c = 0; c < CHK; ++c) {
        float v = f[(size_t)c * DST];
        f[(size_t)c * DST] = x;                        // exclusive carry-in
        x = fmaf(lamL, x, v);
    }
}

__global__ __launch_bounds__(256)
void scan3_kernel(unsigned short* __restrict__ up,
                  const float* __restrict__ logl,
                  const float* __restrict__ fin)
{
    const int gid = blockIdx.x * 256 + threadIdx.x;
    const int sp  = gid & (DST / 2 - 1);
    const int bc  = gid >> 10;
    const int c   = bc & (CHK - 1), b = bc >> 5;
    const int s0  = sp * 2;
    const float lam0 = sigm(logl[s0]),  lam1 = sigm(logl[s0 + 1]);
    const float o0 = 1.f - lam0, o1 = 1.f - lam1;
    const float2 cv = reinterpret_cast<const float2*>(fin + (size_t)bc * DST + s0)[0];
    float x0 = cv.x, x1 = cv.y;
    ushort2* p = reinterpret_cast<ushort2*>(
        up + ((size_t)b * TT + (size_t)c * CLEN) * DST + s0);
    for (int t = 0; t < CLEN; ++t) {
        ushort2 v = p[(size_t)t * (DST / 2)];
        x0 = fmaf(lam0, x0, o0 * bf2f(v.x));
        x1 = fmaf(lam1, x1, o1 * bf2f(v.y));
        p[(size_t)t * (DST / 2)] = make_ushort2(f2bf(x0), f2bf(x1));
    }
}

// ---------------------------------------------------------------------------
extern "C" void kernel_launch(void* const* d_in, const int* in_sizes, int n_in,
                              void* d_out, int out_size, void* d_ws, size_t ws_size,
                              hipStream_t stream)
{
    const float* u     = (const float*)d_in[0];   // B,T,DIN
    const float* W_in  = (const float*)d_in[1];   // DST,DIN
    const float* logl  = (const float*)d_in[2];   // DST
    const float* W_out = (const float*)d_in[3];   // DIN,DST
    const float* Dv    = (const float*)d_in[4];   // DIN
    float* y = (float*)d_out;

    char* ws = (char*)d_ws;
    unsigned short* uA  = (unsigned short*)(ws);                      // 32 MiB
    unsigned short* wA  = (unsigned short*)(ws + (32ull << 20));      //  4 MiB
    unsigned short* wB  = (unsigned short*)(ws + (36ull << 20));      //  4 MiB
    unsigned short* upb = (unsigned short*)(ws + (40ull << 20));      // 64 MiB
    float*          fin = (float*)(ws + (104ull << 20));              //  1 MiB

    // fused fp32 -> bf16 conversions (one launch)
    cvt_all_kernel<<<(N_U4 + 2 * N_W4) / 256, 256, 0, stream>>>(
        u, W_in, W_out, uA, wA, wB);

    // GEMM1: u_proj (raw, unscaled) -> upb bf16
    gemm_m97<DIN, DST / 128, false><<<(MM / 128) * (DST / 128), 256, 0, stream>>>(
        uA, wA, upb, nullptr, nullptr, nullptr);

    // chunked diagonal scan, in place on upb
    scan1_kernel<<<(BB * CHK * DST / 2) / 256, 256, 0, stream>>>(upb, logl, fin);
    scan2_kernel<<<(BB * DST) / 256, 256, 0, stream>>>(fin, logl);
    scan3_kernel<<<(BB * CHK * DST / 2) / 256, 256, 0, stream>>>(upb, logl, fin);

    // GEMM2: y = xs @ W_out^T + uA*D   (U read as bf16)
    gemm_m97<DST, DIN / 128, true><<<(MM / 128) * (DIN / 128), 256, 0, stream>>>(
        upb, wB, nullptr, y, uA, Dv);
}

// Round 11
// 191.453 us; speedup vs baseline: 1.0217x; 1.0217x over previous
//
#include <hip/hip_runtime.h>
#include <math.h>

#define BB   4
#define TT   4096
#define DIN  1024
#define DST  2048
#define MM   (BB*TT)     // 16384
#define CHK  32          // scan chunks per sequence
#define CLEN (TT/CHK)    // 128  (== GEMM1 BM, so M-tile bm <-> chunk bc identity)

typedef __bf16 bf16x8 __attribute__((ext_vector_type(8)));
typedef float  f32x4  __attribute__((ext_vector_type(4)));

__device__ __forceinline__ unsigned short f2bf(float f) {
    union { float f; unsigned u; } v; v.f = f;
    unsigned r = v.u + 0x7FFFu + ((v.u >> 16) & 1u);   // RNE
    return (unsigned short)(r >> 16);
}
__device__ __forceinline__ float bf2f(unsigned short h) {
    union { unsigned u; float f; } v; v.u = ((unsigned)h) << 16;
    return v.f;
}
__device__ __forceinline__ float sigm(float x) { return 1.f / (1.f + __expf(-x)); }

// ---------------------------------------------------------------------------
// fused fp32 -> bf16 conversion of u, W_in, W_out in ONE launch.
// ---------------------------------------------------------------------------
#define N_U4 (MM * DIN / 4)          // 4,194,304
#define N_W4 (DST * DIN / 4)         //   524,288

__global__ __launch_bounds__(256)
void cvt_all_kernel(const float* __restrict__ u,
                    const float* __restrict__ W_in,
                    const float* __restrict__ W_out,
                    unsigned short* __restrict__ uA,
                    unsigned short* __restrict__ wA,
                    unsigned short* __restrict__ wB)
{
    int i = blockIdx.x * 256 + threadIdx.x;
    const float* src; unsigned short* dst; int idx;
    if (i < N_U4)                { src = u;     dst = uA; idx = i; }
    else if (i < N_U4 + N_W4)    { src = W_in;  dst = wA; idx = i - N_U4; }
    else                         { src = W_out; dst = wB; idx = i - N_U4 - N_W4; }
    float4 f = reinterpret_cast<const float4*>(src)[idx];
    ushort4 o;
    o.x = f2bf(f.x); o.y = f2bf(f.y); o.z = f2bf(f.z); o.w = f2bf(f.w);
    reinterpret_cast<ushort4*>(dst)[idx] = o;
}

// ---------------------------------------------------------------------------
// m97-structure bf16 NT MFMA GEMM (886 TF measured R9): 128x128 tile, BK=64,
// 4 waves (2x2), wave tile 64x64, single 32 KiB LDS buffer, 2-barrier loop,
// 3 blocks/CU. XOR swizzle col8 ^= (row&7) both-sides (0-conflict).
// FUSE=false (GEMM1): Obf = bf16(acc); ALSO emits chunk-final
//     fin[bm][s] = sum_t lam_s^{127-t} (1-lam_s) acc[t][s]
//   (tile rows == chunk t-range; weighted reduce of acc, shfl+LDS, 1 store).
// FUSE=true  (GEMM2): Of = acc + bf2f(Ubf)*Dv[col].
// ---------------------------------------------------------------------------
template<int K, int NB, bool FUSE>
__global__ __launch_bounds__(256, 3)
void gemm_m97(const unsigned short* __restrict__ A,
              const unsigned short* __restrict__ B,
              unsigned short* __restrict__ Obf,
              float* __restrict__ Of,
              const unsigned short* __restrict__ Ubf,
              const float* __restrict__ Dv,
              const float* __restrict__ logl,
              float* __restrict__ fin)
{
    constexpr int N  = NB * 128;
    constexpr int NT = K / 64;
    __shared__ __align__(16) unsigned short lds[16384];   // A 16KB + B 16KB

    // XCD-aware bijective swizzle (nwg % 8 == 0: 2048 / 1024 blocks)
    const int nwg = gridDim.x;
    const int bid = blockIdx.x;
    const int swz = (bid & 7) * (nwg >> 3) + (bid >> 3);
    const int bm = swz / NB, bn = swz % NB;

    const int tid  = threadIdx.x;
    const int lane = tid & 63;
    const int wid  = tid >> 6;          // 0..3
    const int wr   = wid >> 1;          // 0..1  (64-row band)
    const int wc   = wid & 1;           // 0..1  (64-col band)
    const int fr   = lane & 15, fq = lane >> 4;

    // --- staging: linear LDS dest, pre-swizzled global source col ---
    const int srow = tid >> 3;                                  // 0..31
    const int scol = (((tid & 7) ^ (srow & 7)) << 3);           // swizzled col
    const unsigned short* Ag = A + (size_t)(bm * 128 + srow) * K + scol;
    const unsigned short* Bg = B + (size_t)(bn * 128 + srow) * K + scol;

    auto stage = [&](int t) {
        const size_t kof = (size_t)t * 64;
#pragma unroll
        for (int r = 0; r < 4; ++r)
            __builtin_amdgcn_global_load_lds(
                (const __attribute__((address_space(1))) void*)(Ag + kof + (size_t)(r * 32) * K),
                (__attribute__((address_space(3))) void*)(&lds[r * 2048 + tid * 8]),
                16, 0, 0);
#pragma unroll
        for (int r = 0; r < 4; ++r)
            __builtin_amdgcn_global_load_lds(
                (const __attribute__((address_space(1))) void*)(Bg + kof + (size_t)(r * 32) * K),
                (__attribute__((address_space(3))) void*)(&lds[8192 + r * 2048 + tid * 8]),
                16, 0, 0);
    };

    // --- frag read addressing (read-side swizzle: row&7 == fr&7) ---
    const int c0 = ((fq ^ (fr & 7)) << 3);          // kk=0 col group
    const int c1 = (((4 + fq) ^ (fr & 7)) << 3);    // kk=1 col group
    const int aBase = (wr * 64 + fr) * 64;                  // + m*1024
    const int bBase = 8192 + (wc * 64 + fr) * 64;           // + n*1024

    f32x4 acc[4][4];
#pragma unroll
    for (int m = 0; m < 4; ++m)
#pragma unroll
        for (int n = 0; n < 4; ++n) {
            acc[m][n][0] = 0.f; acc[m][n][1] = 0.f;
            acc[m][n][2] = 0.f; acc[m][n][3] = 0.f;
        }

    for (int t = 0; t < NT; ++t) {
        __syncthreads();            // all reads of buffer done (prev iter)
        stage(t);
        __syncthreads();            // compiler drains vmcnt before barrier

        bf16x8 af[4], bfv[4];
        // kk = 0
#pragma unroll
        for (int m = 0; m < 4; ++m)
            af[m] = *reinterpret_cast<const bf16x8*>(&lds[aBase + m * 1024 + c0]);
#pragma unroll
        for (int n = 0; n < 4; ++n)
            bfv[n] = *reinterpret_cast<const bf16x8*>(&lds[bBase + n * 1024 + c0]);
#pragma unroll
        for (int m = 0; m < 4; ++m)
#pragma unroll
            for (int n = 0; n < 4; ++n)
                acc[m][n] = __builtin_amdgcn_mfma_f32_16x16x32_bf16(
                    af[m], bfv[n], acc[m][n], 0, 0, 0);
        // kk = 1
#pragma unroll
        for (int m = 0; m < 4; ++m)
            af[m] = *reinterpret_cast<const bf16x8*>(&lds[aBase + m * 1024 + c1]);
#pragma unroll
        for (int n = 0; n < 4; ++n)
            bfv[n] = *reinterpret_cast<const bf16x8*>(&lds[bBase + n * 1024 + c1]);
#pragma unroll
        for (int m = 0; m < 4; ++m)
#pragma unroll
            for (int n = 0; n < 4; ++n)
                acc[m][n] = __builtin_amdgcn_mfma_f32_16x16x32_bf16(
                    af[m], bfv[n], acc[m][n], 0, 0, 0);
    }

    // --- epilogue.  C/D layout: col = lane&15, row = fq*4 + reg ---
    const int row0 = bm * 128 + wr * 64 + fq * 4;
    const int col0 = bn * 128 + wc * 64 + fr;
    if (FUSE) {
#pragma unroll
        for (int n = 0; n < 4; ++n) {
            const int col = col0 + n * 16;
            const float d = Dv[col];
#pragma unroll
            for (int m = 0; m < 4; ++m)
#pragma unroll
                for (int r = 0; r < 4; ++r) {
                    const size_t idx = (size_t)(row0 + m * 16 + r) * N + col;
                    Of[idx] = acc[m][n][r] + bf2f(Ubf[idx]) * d;
                }
        }
    } else {
#pragma unroll
        for (int m = 0; m < 4; ++m)
#pragma unroll
            for (int r = 0; r < 4; ++r) {
                const size_t ro = (size_t)(row0 + m * 16 + r) * N;
#pragma unroll
                for (int n = 0; n < 4; ++n)
                    Obf[ro + col0 + n * 16] = f2bf(acc[m][n][r]);
            }

        // ---- fused scan1: chunk-final F[bm][s] from fp32 acc ----
        // row_local = wr*64 + fq*4 + m*16 + r; weight = lam^(127-row)*(1-lam)
        //           = w0 * li^(m*16+r),  w0 = lam^(127-wr*64-fq*4)*(1-lam)
        float p[4];
#pragma unroll
        for (int n = 0; n < 4; ++n) {
            const int col = bn * 128 + wc * 64 + n * 16 + fr;
            const float lam = sigm(logl[col]);
            const float l2  = log2f(lam);
            const float e0  = (float)(127 - (wr * 64 + fq * 4));
            float w0 = exp2f(e0 * l2) * (1.f - lam);
            const float li  = 1.f / lam;
            const float li2 = li * li, li4 = li2 * li2, li8 = li4 * li4;
            const float li16 = li8 * li8;
            float s = 0.f, wm = w0;
#pragma unroll
            for (int m = 0; m < 4; ++m) {
                float w = wm;
#pragma unroll
                for (int r = 0; r < 4; ++r) {
                    s = fmaf(w, acc[m][n][r], s);
                    w *= li;
                }
                wm *= li16;
            }
            p[n] = s;
        }
        // reduce across fq (lanes ^16, ^32 hold same column)
#pragma unroll
        for (int n = 0; n < 4; ++n) {
            p[n] += __shfl_xor(p[n], 16, 64);
            p[n] += __shfl_xor(p[n], 32, 64);
        }
        __syncthreads();                        // LDS reuse safe
        float* part = reinterpret_cast<float*>(lds);   // [2][128]
        if (fq == 0) {
#pragma unroll
            for (int n = 0; n < 4; ++n)
                part[wr * 128 + wc * 64 + n * 16 + fr] = p[n];
        }
        __syncthreads();
        if (tid < 128)
            fin[(size_t)bm * DST + bn * 128 + tid] = part[tid] + part[128 + tid];
    }
}

// ---------------------------------------------------------------------------
// scan3 (with inlined carry fold): for chunk c, carry = Horner over F[0..c-1],
// then x_t = lam*x_{t-1} + (1-lam)*up_t in place (bf16).
// fin[bc][s] = chunk-local finals from GEMM1. One thread per (b,c,s-pair).
// ---------------------------------------------------------------------------
__global__ __launch_bounds__(256)
void scan3_kernel(unsigned short* __restrict__ up,
                  const float* __restrict__ logl,
                  const float* __restrict__ fin)
{
    const int gid = blockIdx.x * 256 + threadIdx.x;
    const int sp  = gid & (DST / 2 - 1);
    const int bc  = gid >> 10;                         // b*CHK + c
    const int c   = bc & (CHK - 1), b = bc >> 5;
    const int s0  = sp * 2;
    const float lam0 = sigm(logl[s0]),  lam1 = sigm(logl[s0 + 1]);
    const float o0 = 1.f - lam0, o1 = 1.f - lam1;
    float lamL0 = lam0, lamL1 = lam1;
#pragma unroll
    for (int i = 0; i < 7; ++i) { lamL0 *= lamL0; lamL1 *= lamL1; }   // lam^128

    // carry_in = sum_{c'<c} lamL^(c-1-c') * F[c']   (Horner, ascending c')
    float x0 = 0.f, x1 = 0.f;
    for (int cc = 0; cc < c; ++cc) {
        const float2 F = reinterpret_cast<const float2*>(
            fin + (size_t)(b * CHK + cc) * DST + s0)[0];
        x0 = fmaf(x0, lamL0, F.x);
        x1 = fmaf(x1, lamL1, F.y);
    }

    ushort2* p = reinterpret_cast<ushort2*>(
        up + ((size_t)b * TT + (size_t)c * CLEN) * DST + s0);
    for (int t = 0; t < CLEN; ++t) {
        ushort2 v = p[(size_t)t * (DST / 2)];
        x0 = fmaf(lam0, x0, o0 * bf2f(v.x));
        x1 = fmaf(lam1, x1, o1 * bf2f(v.y));
        p[(size_t)t * (DST / 2)] = make_ushort2(f2bf(x0), f2bf(x1));
    }
}

// ---------------------------------------------------------------------------
extern "C" void kernel_launch(void* const* d_in, const int* in_sizes, int n_in,
                              void* d_out, int out_size, void* d_ws, size_t ws_size,
                              hipStream_t stream)
{
    const float* u     = (const float*)d_in[0];   // B,T,DIN
    const float* W_in  = (const float*)d_in[1];   // DST,DIN
    const float* logl  = (const float*)d_in[2];   // DST
    const float* W_out = (const float*)d_in[3];   // DIN,DST
    const float* Dv    = (const float*)d_in[4];   // DIN
    float* y = (float*)d_out;

    char* ws = (char*)d_ws;
    unsigned short* uA  = (unsigned short*)(ws);                      // 32 MiB
    unsigned short* wA  = (unsigned short*)(ws + (32ull << 20));      //  4 MiB
    unsigned short* wB  = (unsigned short*)(ws + (36ull << 20));      //  4 MiB
    unsigned short* upb = (unsigned short*)(ws + (40ull << 20));      // 64 MiB
    float*          fin = (float*)(ws + (104ull << 20));              //  1 MiB

    // fused fp32 -> bf16 conversions (one launch)
    cvt_all_kernel<<<(N_U4 + 2 * N_W4) / 256, 256, 0, stream>>>(
        u, W_in, W_out, uA, wA, wB);

    // GEMM1: u_proj -> upb bf16, PLUS chunk-finals fin (fused scan1)
    gemm_m97<DIN, DST / 128, false><<<(MM / 128) * (DST / 128), 256, 0, stream>>>(
        uA, wA, upb, nullptr, nullptr, nullptr, logl, fin);

    // scan3 (carry fold inlined): in-place recurrence on upb
    scan3_kernel<<<(BB * CHK * DST / 2) / 256, 256, 0, stream>>>(upb, logl, fin);

    // GEMM2: y = xs @ W_out^T + uA*D   (U read as bf16)
    gemm_m97<DST, DIN / 128, true><<<(MM / 128) * (DIN / 128), 256, 0, stream>>>(
        upb, wB, nullptr, y, uA, Dv, nullptr, nullptr);
}